// Round 5
// baseline (225.895 us; speedup 1.0000x reference)
//
#include <hip/hip_runtime.h>

typedef float floatx4 __attribute__((ext_vector_type(4)));
typedef __bf16 bfx8 __attribute__((ext_vector_type(8)));
typedef __bf16 bfx4 __attribute__((ext_vector_type(4)));

// Problem constants
constexpr int B_ = 2, S_ = 2048, H_ = 2048, NH_ = 16, NKV_ = 4, HD_ = 64;
constexpr int M_ = B_ * S_;               // 4096 rows
constexpr int NQKV_ = NH_ * HD_ + 2 * NKV_ * HD_; // 1536
constexpr int HQ_ = NH_ * HD_;            // 1024
// Pitches: 128B-aligned (no cache-line straddle on 128B DMA row-chunks) AND an
// odd multiple of 64 elements (33x128B / 17x128B) to keep channel spread.
constexpr int XP_ = 2112;  // xbf / wqkvT pitch (4224B = 33*128)
constexpr int AP_ = 1088;  // attn-out / woT pitch (2176B = 17*128)
constexpr int VP_ = 2112;  // V-transposed pitch
// split-K partial stride (elements) for the QKV GEMM
constexpr int QKV_ELEMS_ = M_ * NQKV_;    // 6,291,456
// 0.125/sqrt-d scale * log2(e), folded into Q at norm_rope so the attn inner loop
// is a bare v_exp_f32 (exp2). Q is bf16-rounded either way -> identical error structure.
constexpr float QSCL_ = 0.125f * 1.44269504088896340736f;

#define GLB(p) ((const __attribute__((address_space(1))) void*)(p))
#define LDS(p) ((__attribute__((address_space(3))) void*)(p))

// ---------------- fused prep: fp32->bf16 cast of x  +  all 4 weight transposes ----------
__global__ __launch_bounds__(256) void prep_kernel(const float* __restrict__ x,
                                                   const float* __restrict__ wq,
                                                   const float* __restrict__ wk,
                                                   const float* __restrict__ wv,
                                                   const float* __restrict__ wo,
                                                   __bf16* __restrict__ xbf,
                                                   __bf16* __restrict__ wqkvT,
                                                   __bf16* __restrict__ woT) {
  __shared__ float tile[32][33];
  int bid = blockIdx.x;
  if (bid < M_) {
    // ---- cast branch ----
    const float4* s = (const float4*)(x + (size_t)bid * H_);
    __bf16* d = xbf + (size_t)bid * XP_;
#pragma unroll
    for (int i = 0; i < 2; i++) {
      int c = i * 256 + threadIdx.x;
      float4 v = s[c];
      bfx4 o;
      o[0] = (__bf16)v.x; o[1] = (__bf16)v.y; o[2] = (__bf16)v.z; o[3] = (__bf16)v.w;
      *(bfx4*)(d + c * 4) = o;
    }
    return;
  }
  bid -= M_;
  const float* src; __bf16* dst; int N, dstOff, pitch, nbx;
  if (bid < 2048)      { src = wq; dst = wqkvT; N = 1024; dstOff = 0;    pitch = XP_; nbx = 32; }
  else if (bid < 2560) { bid -= 2048; src = wk; dst = wqkvT; N = 256; dstOff = 1024; pitch = XP_; nbx = 8; }
  else if (bid < 3072) { bid -= 2560; src = wv; dst = wqkvT; N = 256; dstOff = 1280; pitch = XP_; nbx = 8; }
  else                 { bid -= 3072; src = wo; dst = woT;   N = 2048; dstOff = 0;   pitch = AP_; nbx = 64; }
  int n0 = (bid % nbx) * 32, k0 = (bid / nbx) * 32;
  int tx = threadIdx.x & 31, ty = threadIdx.x >> 5; // (32,8) layout
#pragma unroll
  for (int r = 0; r < 32; r += 8)
    tile[ty + r][tx] = src[(size_t)(k0 + ty + r) * N + n0 + tx];
  __syncthreads();
#pragma unroll
  for (int r = 0; r < 32; r += 8)
    dst[(size_t)(n0 + ty + r + dstOff) * pitch + k0 + tx] = (__bf16)tile[tx][ty + r];
}

// ---------------- bf16 MFMA GEMM: 256x128 tile, BK=64, 8 waves (4m x 2n) ------------
// A: MxK (lda), Bt: NxK (ldb), C: MxN fp32 (ldc). LDS unpadded (DMA dest =
// wave-uniform base + lane*16); XOR swizzle applied to the SOURCE address, undone on
// the fragment read. Split-K via blockIdx.z: [z*K,(z+1)*K) -> C + z*cstride.
__global__ __launch_bounds__(512) void gemm_bf16_f32(const __bf16* __restrict__ A,
                                                     const __bf16* __restrict__ Bt,
                                                     float* __restrict__ C,
                                                     int M, int N, int K,
                                                     int lda, int ldb, int ldc,
                                                     unsigned long long cstride) {
  __shared__ __align__(16) __bf16 As[256 * 64];
  __shared__ __align__(16) __bf16 Bs[128 * 64];
  int wid = threadIdx.x >> 6, lane = threadIdx.x & 63;
  int l15 = lane & 15, quad = lane >> 4;
  int wm = (wid >> 1) * 64, wn = (wid & 1) * 64; // 4m x 2n wave grid
  int m0 = blockIdx.y * 256, n0 = blockIdx.x * 128;
  int kb0 = blockIdx.z * K;
  C += (size_t)blockIdx.z * cstride;
  int srow_off = lane >> 3;  // 8 lanes per 64-col row (16B each)
  int gphys = lane & 7;
  floatx4 acc[4][4] = {};
  for (int kb = kb0; kb < kb0 + K; kb += 64) {
#pragma unroll
    for (int j = 0; j < 4; j++) {
      int rbase = j * 64 + wid * 8;
      int row = rbase + srow_off;
      int glog = gphys ^ (row & 7);
      const __bf16* ga = &A[(size_t)(m0 + row) * lda + kb + glog * 8];
      __builtin_amdgcn_global_load_lds(GLB(ga), LDS(&As[rbase * 64]), 16, 0, 0);
    }
#pragma unroll
    for (int j = 0; j < 2; j++) {
      int rbase = j * 64 + wid * 8;
      int row = rbase + srow_off;
      int glog = gphys ^ (row & 7);
      const __bf16* gb = &Bt[(size_t)(n0 + row) * ldb + kb + glog * 8];
      __builtin_amdgcn_global_load_lds(GLB(gb), LDS(&Bs[rbase * 64]), 16, 0, 0);
    }
    __syncthreads(); // compiler emits vmcnt(0) drain before barrier
#pragma unroll
    for (int kk = 0; kk < 64; kk += 32) {
      int cgq = (kk >> 3) + quad; // logical 16B-group of this quad's fragment
      bfx8 af[4], bfr[4];
#pragma unroll
      for (int mi = 0; mi < 4; mi++) {
        int row = wm + mi * 16 + l15;
        af[mi] = *(const bfx8*)&As[row * 64 + (cgq ^ (row & 7)) * 8];
      }
#pragma unroll
      for (int ni = 0; ni < 4; ni++) {
        int row = wn + ni * 16 + l15;
        bfr[ni] = *(const bfx8*)&Bs[row * 64 + (cgq ^ (row & 7)) * 8];
      }
#pragma unroll
      for (int mi = 0; mi < 4; mi++)
#pragma unroll
        for (int ni = 0; ni < 4; ni++)
          acc[mi][ni] = __builtin_amdgcn_mfma_f32_16x16x32_bf16(af[mi], bfr[ni], acc[mi][ni], 0, 0, 0);
    }
    __syncthreads();
  }
#pragma unroll
  for (int mi = 0; mi < 4; mi++)
#pragma unroll
    for (int ni = 0; ni < 4; ni++) {
      int row = m0 + wm + mi * 16 + quad * 4;
      int coln = n0 + wn + ni * 16 + l15;
#pragma unroll
      for (int r = 0; r < 4; r++)
        C[(size_t)(row + r) * ldc + coln] = acc[mi][ni][r];
    }
}

// ---------------- RMSNorm + RoPE on q/k, cast+layout for attention ----------------
// Reads TWO split-K partials of qkv and sums them (split-K reduction fused here).
// Q rows are additionally scaled by QSCL_ (softmax scale * log2e) -> attn uses exp2.
__global__ __launch_bounds__(256) void norm_rope_kernel(const float* __restrict__ qkv,
                                                        const float* __restrict__ cosT,
                                                        const float* __restrict__ sinT,
                                                        const float* __restrict__ qw,
                                                        const float* __restrict__ kw,
                                                        __bf16* __restrict__ Qo,
                                                        __bf16* __restrict__ Ko,
                                                        __bf16* __restrict__ VTo) {
  int s = blockIdx.x, b = blockIdx.y;
  int wid = threadIdx.x >> 6, lane = threadIdx.x & 63;
  const float* rowp = qkv + (size_t)(b * S_ + s) * NQKV_;
  const float* rowp2 = rowp + QKV_ELEMS_;
  float c = cosT[s * HD_ + lane];
  float sn = sinT[s * HD_ + lane];
#pragma unroll
  for (int it = 0; it < 5; it++) {
    int hh = it * 4 + wid; // 0..15 q heads, 16..19 k heads
    int idx = hh * 64 + lane;
    float v = rowp[idx] + rowp2[idx];
    float ss = v * v;
#pragma unroll
    for (int off = 1; off < 64; off <<= 1) ss += __shfl_xor(ss, off);
    float rs = rsqrtf(ss * (1.0f / 64.0f) + 1e-6f);
    const float* w = (hh < 16) ? qw : kw;
    float nv = v * rs * w[lane];
    float other = __shfl_xor(nv, 32);
    float rot = (lane < 32) ? -other : other; // rotate_half
    float outv = nv * c + rot * sn;
    if (hh < 16)
      Qo[(((size_t)b * NH_ + hh) * S_ + s) * HD_ + lane] = (__bf16)(outv * QSCL_);
    else
      Ko[(((size_t)b * NKV_ + (hh - 16)) * S_ + s) * HD_ + lane] = (__bf16)outv;
  }
  {
    int idx = (20 + wid) * 64 + lane;
    float v = rowp[idx] + rowp2[idx];
    VTo[(((size_t)b * NKV_ + wid) * HD_ + lane) * VP_ + s] = (__bf16)v;
  }
}

// ---------------- flash attention (causal, GQA), block-cooperative LDS staging ----------
// Round-2 proven structure (4 waves, QBLK=64, reg-staged double-buffer) + VALU cuts:
//  - Q pre-scaled -> inner loop is bare exp2f (v_exp_f32), no per-element mul
//  - causal mask peeled: only the LAST tile (kt==ntiles-1, block-uniform) runs cmp/cndmask
//  - s_setprio(1) around MFMA clusters (T5; blocks at different kt phases co-resident)
__global__ __launch_bounds__(256, 4) void attn_kernel(const __bf16* __restrict__ Q,
                                                      const __bf16* __restrict__ Kc,
                                                      const __bf16* __restrict__ VT,
                                                      __bf16* __restrict__ Ob) {
  int px = blockIdx.x, h = blockIdx.y, b = blockIdx.z;
  int u = (px + 2 * (h & 7)) & 31;
  int qt = (((h >> 3) ^ b) & 1) ? (31 - u) : u;
  int wid = threadIdx.x >> 6, lane = threadIdx.x & 63;
  int l15 = lane & 15, quad = lane >> 4;
  int q0 = qt * 64 + wid * 16;
  int kvh = h >> 2; // N_REP = 4
  const __bf16* Qh = Q + (((size_t)b * NH_ + h) * S_ + q0) * HD_;
  const __bf16* Kh = Kc + ((size_t)b * NKV_ + kvh) * S_ * HD_;
  const __bf16* Vh = VT + ((size_t)b * NKV_ + kvh) * (size_t)HD_ * VP_;
  __shared__ __align__(16) __bf16 Ks[64][72]; // [kv][hd]
  __shared__ __align__(16) __bf16 Vs[64][72]; // [hd][kv]
  __shared__ __align__(16) __bf16 Pst[4][16][72];
  __bf16 (*P)[72] = Pst[wid];

  int srow = threadIdx.x >> 3;         // 0..31
  int scol = (threadIdx.x & 7) * 8;    // element offset 0..56

  bfx8 qf0, qf1;
  {
    const __bf16* qp = Qh + l15 * HD_ + quad * 8;
    qf0 = *(const bfx8*)qp;
    qf1 = *(const bfx8*)(qp + 32);
  }
  floatx4 oacc[4] = {};
  float ps = 0.f;
  int ntiles = qt + 1; // causal, block-uniform
  bfx8 kpre0, kpre1, vpre0, vpre1;
  kpre0 = *(const bfx8*)&Kh[(size_t)srow * HD_ + scol];
  kpre1 = *(const bfx8*)&Kh[(size_t)(srow + 32) * HD_ + scol];
  vpre0 = *(const bfx8*)&Vh[(size_t)srow * VP_ + scol];
  vpre1 = *(const bfx8*)&Vh[(size_t)(srow + 32) * VP_ + scol];
  for (int kt = 0; kt < ntiles; kt++) {
    int kv0 = kt * 64;
    __syncthreads();
    *(bfx8*)&Ks[srow][scol] = kpre0;
    *(bfx8*)&Ks[srow + 32][scol] = kpre1;
    *(bfx8*)&Vs[srow][scol] = vpre0;
    *(bfx8*)&Vs[srow + 32][scol] = vpre1;
    __syncthreads();
    if (kt + 1 < ntiles) {
      int kn = kv0 + 64;
      kpre0 = *(const bfx8*)&Kh[(size_t)(kn + srow) * HD_ + scol];
      kpre1 = *(const bfx8*)&Kh[(size_t)(kn + srow + 32) * HD_ + scol];
      vpre0 = *(const bfx8*)&Vh[(size_t)srow * VP_ + kn + scol];
      vpre1 = *(const bfx8*)&Vh[(size_t)(srow + 32) * VP_ + kn + scol];
    }
    floatx4 sf[4];
    __builtin_amdgcn_s_setprio(1);
#pragma unroll
    for (int nt = 0; nt < 4; nt++) {
      bfx8 kf0 = *(const bfx8*)&Ks[nt * 16 + l15][quad * 8];
      bfx8 kf1 = *(const bfx8*)&Ks[nt * 16 + l15][32 + quad * 8];
      floatx4 z = {0.f, 0.f, 0.f, 0.f};
      z = __builtin_amdgcn_mfma_f32_16x16x32_bf16(kf0, qf0, z, 0, 0, 0);
      sf[nt] = __builtin_amdgcn_mfma_f32_16x16x32_bf16(kf1, qf1, z, 0, 0, 0);
    }
    __builtin_amdgcn_s_setprio(0);
    if (kt + 1 < ntiles) {
      // interior tile: no causal masking needed (q0 - kv0 >= 64 > any kvrel-l15)
#pragma unroll
      for (int nt = 0; nt < 4; nt++) {
        bfx4 pk;
#pragma unroll
        for (int r = 0; r < 4; r++) {
          float p = exp2f(sf[nt][r]);
          ps += p;
          pk[r] = (__bf16)p;
        }
        *(bfx4*)&P[l15][nt * 16 + quad * 4] = pk;
      }
    } else {
      int dq = q0 - kv0; // = wid*16, the single partial (diagonal) tile
#pragma unroll
      for (int nt = 0; nt < 4; nt++) {
        bfx4 pk;
#pragma unroll
        for (int r = 0; r < 4; r++) {
          int kvrel = nt * 16 + quad * 4 + r;
          float p = exp2f(sf[nt][r]);
          p = (kvrel - l15 > dq) ? 0.f : p;
          ps += p;
          pk[r] = (__bf16)p;
        }
        *(bfx4*)&P[l15][nt * 16 + quad * 4] = pk;
      }
    }
    bfx8 pa0 = *(const bfx8*)&P[l15][quad * 8];
    bfx8 pa1 = *(const bfx8*)&P[l15][32 + quad * 8];
    __builtin_amdgcn_s_setprio(1);
#pragma unroll
    for (int ot = 0; ot < 4; ot++) {
      bfx8 vf0 = *(const bfx8*)&Vs[ot * 16 + l15][quad * 8];
      bfx8 vf1 = *(const bfx8*)&Vs[ot * 16 + l15][32 + quad * 8];
      oacc[ot] = __builtin_amdgcn_mfma_f32_16x16x32_bf16(pa0, vf0, oacc[ot], 0, 0, 0);
      oacc[ot] = __builtin_amdgcn_mfma_f32_16x16x32_bf16(pa1, vf1, oacc[ot], 0, 0, 0);
    }
    __builtin_amdgcn_s_setprio(0);
  }
  ps += __shfl_xor(ps, 16);
  ps += __shfl_xor(ps, 32);
  float rl[4];
#pragma unroll
  for (int r = 0; r < 4; r++) rl[r] = 1.0f / __shfl(ps, quad * 4 + r);
#pragma unroll
  for (int ot = 0; ot < 4; ot++)
#pragma unroll
    for (int r = 0; r < 4; r++) {
      float val = oacc[ot][r] * rl[r];
      Ob[((size_t)b * S_ + q0 + quad * 4 + r) * AP_ + h * HD_ + ot * 16 + l15] = (__bf16)val;
    }
}

extern "C" void kernel_launch(void* const* d_in, const int* in_sizes, int n_in,
                              void* d_out, int out_size, void* d_ws, size_t ws_size,
                              hipStream_t stream) {
  const float* x   = (const float*)d_in[0];
  const float* cosT = (const float*)d_in[1];
  const float* sinT = (const float*)d_in[2];
  const float* wq  = (const float*)d_in[3];
  const float* wk  = (const float*)d_in[4];
  const float* wv  = (const float*)d_in[5];
  const float* wo  = (const float*)d_in[6];
  const float* qw  = (const float*)d_in[7];
  const float* kw  = (const float*)d_in[8];
  float* out = (float*)d_out;

  char* w = (char*)d_ws;
  // Lifetime-packed workspace:
  //   xbf [0, 17,301,504)  dead after gemm1; Qb/Kb/VTb reuse it (written by norm_rope)
  __bf16* xbf   = (__bf16*)(w);                        // 4096*2112*2 = 17,301,504
  __bf16* Qb    = (__bf16*)(w);                        //  8,388,608 (aliases dead xbf)
  __bf16* Kb    = (__bf16*)(w + 8388608);              //  2,097,152
  __bf16* VTb   = (__bf16*)(w + 10485760);             //  2*4*64*2112*2 = 2,162,688 (end 12,648,448)
  __bf16* wqkvT = (__bf16*)(w + 17301504);             // 1536*2112*2 = 6,488,064
  __bf16* woT   = (__bf16*)(w + 23789568);             // 2048*1088*2 = 4,456,448
  float*  qkv   = (float*) (w + 28246016);             // 2 splits * 4096*1536*4 = 50,331,648
  __bf16* attnO = (__bf16*)(w + 28246016);             // aliases qkv (dead after norm_rope)
                                                       // total end = 78,577,664

  // fused prep: cast (4096 blocks) + wq/wk/wv/wo transposes (2048+512+512+2048)
  prep_kernel<<<M_ + 5120, 256, 0, stream>>>(x, wq, wk, wv, wo, xbf, wqkvT, woT);
  // QKV GEMM, 256x128 tile, split-K=2: grid 12 x 16 x 2 = 384 blocks
  gemm_bf16_f32<<<dim3(NQKV_ / 128, M_ / 256, 2), 512, 0, stream>>>(
      xbf, wqkvT, qkv, M_, NQKV_, H_ / 2, XP_, XP_, NQKV_, (unsigned long long)QKV_ELEMS_);
  norm_rope_kernel<<<dim3(S_, B_), 256, 0, stream>>>(qkv, cosT, sinT, qw, kw, Qb, Kb, VTb);
  // attention: QBLK=64, 4 waves, grid 32 x 16 x 2 = 1024 blocks
  attn_kernel<<<dim3(32, NH_, B_), 256, 0, stream>>>(Qb, Kb, VTb, attnO);
  // output GEMM, 256x128 tile: grid 16 x 16 = 256 blocks
  gemm_bf16_f32<<<dim3(H_ / 128, M_ / 256, 1), 512, 0, stream>>>(
      attnO, woT, out, M_, H_, HQ_, AP_, AP_, H_, 0ull);
}

// Round 6
// 225.354 us; speedup vs baseline: 1.0024x; 1.0024x over previous
//
#include <hip/hip_runtime.h>

typedef float floatx4 __attribute__((ext_vector_type(4)));
typedef __bf16 bfx8 __attribute__((ext_vector_type(8)));
typedef __bf16 bfx4 __attribute__((ext_vector_type(4)));

// Problem constants
constexpr int B_ = 2, S_ = 2048, H_ = 2048, NH_ = 16, NKV_ = 4, HD_ = 64;
constexpr int M_ = B_ * S_;               // 4096 rows
constexpr int NQKV_ = NH_ * HD_ + 2 * NKV_ * HD_; // 1536
constexpr int HQ_ = NH_ * HD_;            // 1024
// Pitches: 128B-aligned (no cache-line straddle on 128B DMA row-chunks) AND an
// odd multiple of 64 elements (33x128B / 17x128B) to keep channel spread.
constexpr int XP_ = 2112;  // xbf / wqkvT pitch (4224B = 33*128)
constexpr int AP_ = 1088;  // attn-out / woT pitch (2176B = 17*128)
constexpr int VP_ = 2112;  // V-transposed pitch
// split-K partial stride (elements) for the QKV GEMM
constexpr int QKV_ELEMS_ = M_ * NQKV_;    // 6,291,456
// 0.125 scale * log2(e), folded into Q at norm_rope so the attn inner loop is a
// bare v_exp_f32 (exp2). Q is bf16-rounded either way -> same error structure.
constexpr float QSCL_ = 0.125f * 1.44269504088896340736f;

#define GLB(p) ((const __attribute__((address_space(1))) void*)(p))
#define LDS(p) ((__attribute__((address_space(3))) void*)(p))

// ---------------- fused prep: fp32->bf16 cast of x  +  all 4 weight transposes ----------
__global__ __launch_bounds__(256) void prep_kernel(const float* __restrict__ x,
                                                   const float* __restrict__ wq,
                                                   const float* __restrict__ wk,
                                                   const float* __restrict__ wv,
                                                   const float* __restrict__ wo,
                                                   __bf16* __restrict__ xbf,
                                                   __bf16* __restrict__ wqkvT,
                                                   __bf16* __restrict__ woT) {
  __shared__ float tile[32][33];
  int bid = blockIdx.x;
  if (bid < M_) {
    // ---- cast branch ----
    const float4* s = (const float4*)(x + (size_t)bid * H_);
    __bf16* d = xbf + (size_t)bid * XP_;
#pragma unroll
    for (int i = 0; i < 2; i++) {
      int c = i * 256 + threadIdx.x;
      float4 v = s[c];
      bfx4 o;
      o[0] = (__bf16)v.x; o[1] = (__bf16)v.y; o[2] = (__bf16)v.z; o[3] = (__bf16)v.w;
      *(bfx4*)(d + c * 4) = o;
    }
    return;
  }
  bid -= M_;
  const float* src; __bf16* dst; int N, dstOff, pitch, nbx;
  if (bid < 2048)      { src = wq; dst = wqkvT; N = 1024; dstOff = 0;    pitch = XP_; nbx = 32; }
  else if (bid < 2560) { bid -= 2048; src = wk; dst = wqkvT; N = 256; dstOff = 1024; pitch = XP_; nbx = 8; }
  else if (bid < 3072) { bid -= 2560; src = wv; dst = wqkvT; N = 256; dstOff = 1280; pitch = XP_; nbx = 8; }
  else                 { bid -= 3072; src = wo; dst = woT;   N = 2048; dstOff = 0;   pitch = AP_; nbx = 64; }
  int n0 = (bid % nbx) * 32, k0 = (bid / nbx) * 32;
  int tx = threadIdx.x & 31, ty = threadIdx.x >> 5; // (32,8) layout
#pragma unroll
  for (int r = 0; r < 32; r += 8)
    tile[ty + r][tx] = src[(size_t)(k0 + ty + r) * N + n0 + tx];
  __syncthreads();
#pragma unroll
  for (int r = 0; r < 32; r += 8)
    dst[(size_t)(n0 + ty + r + dstOff) * pitch + k0 + tx] = (__bf16)tile[tx][ty + r];
}

// ---------------- bf16 MFMA GEMM: 256x128 tile, BK=64, 8 waves (4m x 2n) ------------
// A: MxK (lda), Bt: NxK (ldb), C: MxN fp32 (ldc). LDS unpadded (DMA dest =
// wave-uniform base + lane*16); XOR swizzle applied to the SOURCE address, undone on
// the fragment read. Split-K via blockIdx.z: [z*K,(z+1)*K) -> C + z*cstride.
__global__ __launch_bounds__(512) void gemm_bf16_f32(const __bf16* __restrict__ A,
                                                     const __bf16* __restrict__ Bt,
                                                     float* __restrict__ C,
                                                     int M, int N, int K,
                                                     int lda, int ldb, int ldc,
                                                     unsigned long long cstride) {
  __shared__ __align__(16) __bf16 As[256 * 64];
  __shared__ __align__(16) __bf16 Bs[128 * 64];
  int wid = threadIdx.x >> 6, lane = threadIdx.x & 63;
  int l15 = lane & 15, quad = lane >> 4;
  int wm = (wid >> 1) * 64, wn = (wid & 1) * 64; // 4m x 2n wave grid
  int m0 = blockIdx.y * 256, n0 = blockIdx.x * 128;
  int kb0 = blockIdx.z * K;
  C += (size_t)blockIdx.z * cstride;
  int srow_off = lane >> 3;  // 8 lanes per 64-col row (16B each)
  int gphys = lane & 7;
  floatx4 acc[4][4] = {};
  for (int kb = kb0; kb < kb0 + K; kb += 64) {
#pragma unroll
    for (int j = 0; j < 4; j++) {
      int rbase = j * 64 + wid * 8;
      int row = rbase + srow_off;
      int glog = gphys ^ (row & 7);
      const __bf16* ga = &A[(size_t)(m0 + row) * lda + kb + glog * 8];
      __builtin_amdgcn_global_load_lds(GLB(ga), LDS(&As[rbase * 64]), 16, 0, 0);
    }
#pragma unroll
    for (int j = 0; j < 2; j++) {
      int rbase = j * 64 + wid * 8;
      int row = rbase + srow_off;
      int glog = gphys ^ (row & 7);
      const __bf16* gb = &Bt[(size_t)(n0 + row) * ldb + kb + glog * 8];
      __builtin_amdgcn_global_load_lds(GLB(gb), LDS(&Bs[rbase * 64]), 16, 0, 0);
    }
    __syncthreads(); // compiler emits vmcnt(0) drain before barrier
#pragma unroll
    for (int kk = 0; kk < 64; kk += 32) {
      int cgq = (kk >> 3) + quad; // logical 16B-group of this quad's fragment
      bfx8 af[4], bfr[4];
#pragma unroll
      for (int mi = 0; mi < 4; mi++) {
        int row = wm + mi * 16 + l15;
        af[mi] = *(const bfx8*)&As[row * 64 + (cgq ^ (row & 7)) * 8];
      }
#pragma unroll
      for (int ni = 0; ni < 4; ni++) {
        int row = wn + ni * 16 + l15;
        bfr[ni] = *(const bfx8*)&Bs[row * 64 + (cgq ^ (row & 7)) * 8];
      }
#pragma unroll
      for (int mi = 0; mi < 4; mi++)
#pragma unroll
        for (int ni = 0; ni < 4; ni++)
          acc[mi][ni] = __builtin_amdgcn_mfma_f32_16x16x32_bf16(af[mi], bfr[ni], acc[mi][ni], 0, 0, 0);
    }
    __syncthreads();
  }
#pragma unroll
  for (int mi = 0; mi < 4; mi++)
#pragma unroll
    for (int ni = 0; ni < 4; ni++) {
      int row = m0 + wm + mi * 16 + quad * 4;
      int coln = n0 + wn + ni * 16 + l15;
#pragma unroll
      for (int r = 0; r < 4; r++)
        C[(size_t)(row + r) * ldc + coln] = acc[mi][ni][r];
    }
}

// ---------------- RMSNorm + RoPE on q/k, cast+layout for attention ----------------
// Reads TWO split-K partials of qkv and sums them (split-K reduction fused here).
// Q rows are additionally scaled by QSCL_ (softmax scale * log2e) -> attn uses exp2.
__global__ __launch_bounds__(256) void norm_rope_kernel(const float* __restrict__ qkv,
                                                        const float* __restrict__ cosT,
                                                        const float* __restrict__ sinT,
                                                        const float* __restrict__ qw,
                                                        const float* __restrict__ kw,
                                                        __bf16* __restrict__ Qo,
                                                        __bf16* __restrict__ Ko,
                                                        __bf16* __restrict__ VTo) {
  int s = blockIdx.x, b = blockIdx.y;
  int wid = threadIdx.x >> 6, lane = threadIdx.x & 63;
  const float* rowp = qkv + (size_t)(b * S_ + s) * NQKV_;
  const float* rowp2 = rowp + QKV_ELEMS_;
  float c = cosT[s * HD_ + lane];
  float sn = sinT[s * HD_ + lane];
#pragma unroll
  for (int it = 0; it < 5; it++) {
    int hh = it * 4 + wid; // 0..15 q heads, 16..19 k heads
    int idx = hh * 64 + lane;
    float v = rowp[idx] + rowp2[idx];
    float ss = v * v;
#pragma unroll
    for (int off = 1; off < 64; off <<= 1) ss += __shfl_xor(ss, off);
    float rs = rsqrtf(ss * (1.0f / 64.0f) + 1e-6f);
    const float* w = (hh < 16) ? qw : kw;
    float nv = v * rs * w[lane];
    float other = __shfl_xor(nv, 32);
    float rot = (lane < 32) ? -other : other; // rotate_half
    float outv = nv * c + rot * sn;
    if (hh < 16)
      Qo[(((size_t)b * NH_ + hh) * S_ + s) * HD_ + lane] = (__bf16)(outv * QSCL_);
    else
      Ko[(((size_t)b * NKV_ + (hh - 16)) * S_ + s) * HD_ + lane] = (__bf16)outv;
  }
  {
    int idx = (20 + wid) * 64 + lane;
    float v = rowp[idx] + rowp2[idx];
    VTo[(((size_t)b * NKV_ + wid) * HD_ + lane) * VP_ + s] = (__bf16)v;
  }
}

// ---------------- flash attention (causal, GQA) ----------------
// LDS-bandwidth-targeted restructure: 4 waves x 32 q-rows (QBLK=128). Each wave reads
// K/V fragments ONCE per tile and feeds TWO 16-row MFMA blocks -> LDS bytes per q-row
// halve (the binding resource: ~65% of round-4's 45us was LDS port time).
// Ks/Vs use the GEMM's verified conflict-free XOR layout: pitch 64 (no pad),
// physical 16B-group = logical ^ (row&7), applied on BOTH write and read side
// (reg-staged, no DMA constraint). P keeps pitch 72 (2-way max = free).
// Mask only on the diagonal tile; reg-staged double-buffer prefetch as in round 2.
__global__ __launch_bounds__(256, 2) void attn_kernel(const __bf16* __restrict__ Q,
                                                      const __bf16* __restrict__ Kc,
                                                      const __bf16* __restrict__ VT,
                                                      __bf16* __restrict__ Ob) {
  int px = blockIdx.x, h = blockIdx.y, b = blockIdx.z;
  int u = (px + 2 * (h & 7)) & 15;
  int qt = (((h >> 3) ^ b) & 1) ? (15 - u) : u;
  int wid = threadIdx.x >> 6, lane = threadIdx.x & 63;
  int l15 = lane & 15, quad = lane >> 4;
  int q0w = qt * 128 + wid * 32;      // this wave's first q row
  int kvh = h >> 2; // N_REP = 4
  const __bf16* Qh = Q + (((size_t)b * NH_ + h) * S_ + q0w) * HD_;
  const __bf16* Kh = Kc + ((size_t)b * NKV_ + kvh) * S_ * HD_;
  const __bf16* Vh = VT + ((size_t)b * NKV_ + kvh) * (size_t)HD_ * VP_;
  __shared__ __align__(16) __bf16 Ks[64][64]; // [kv][hd], XOR-swizzled groups
  __shared__ __align__(16) __bf16 Vs[64][64]; // [hd][kv], XOR-swizzled groups
  __shared__ __align__(16) __bf16 Pst[4][32][72];
  __bf16 (*P)[72] = Pst[wid];

  int srow = threadIdx.x >> 3;         // 0..31 staging row
  int sg   = threadIdx.x & 7;          // logical 16B group 0..7
  int pcol = (sg ^ (srow & 7)) * 8;    // physical column ((srow+32)&7 == srow&7)

  bfx8 qf0, qf1, qf2, qf3;             // rows [0,16) and [16,32) of this wave
  {
    const __bf16* qp = Qh + l15 * HD_ + quad * 8;
    qf0 = *(const bfx8*)qp;
    qf1 = *(const bfx8*)(qp + 32);
    qf2 = *(const bfx8*)(qp + 16 * HD_);
    qf3 = *(const bfx8*)(qp + 16 * HD_ + 32);
  }
  floatx4 oacc0[4] = {}, oacc1[4] = {};
  float ps0 = 0.f, ps1 = 0.f;
  int ntiles = 2 * qt + 2;             // block-uniform tile count
  int ktm = 2 * qt + (wid >> 1);       // this wave's diagonal tile
  int dq0 = (wid & 1) * 32;            // diag offset, row-block 0
  int dq1 = dq0 + 16;                  // diag offset, row-block 1

  bfx8 kpre0, kpre1, vpre0, vpre1;
  kpre0 = *(const bfx8*)&Kh[(size_t)srow * HD_ + sg * 8];
  kpre1 = *(const bfx8*)&Kh[(size_t)(srow + 32) * HD_ + sg * 8];
  vpre0 = *(const bfx8*)&Vh[(size_t)srow * VP_ + sg * 8];
  vpre1 = *(const bfx8*)&Vh[(size_t)(srow + 32) * VP_ + sg * 8];
  for (int kt = 0; kt < ntiles; kt++) {
    int kv0 = kt * 64;
    __syncthreads();
    *(bfx8*)&Ks[srow][pcol] = kpre0;
    *(bfx8*)&Ks[srow + 32][pcol] = kpre1;
    *(bfx8*)&Vs[srow][pcol] = vpre0;
    *(bfx8*)&Vs[srow + 32][pcol] = vpre1;
    __syncthreads();
    if (kt + 1 < ntiles) {
      int kn = kv0 + 64;
      kpre0 = *(const bfx8*)&Kh[(size_t)(kn + srow) * HD_ + sg * 8];
      kpre1 = *(const bfx8*)&Kh[(size_t)(kn + srow + 32) * HD_ + sg * 8];
      vpre0 = *(const bfx8*)&Vh[(size_t)srow * VP_ + kn + sg * 8];
      vpre1 = *(const bfx8*)&Vh[(size_t)(srow + 32) * VP_ + kn + sg * 8];
    }
    if (kt > ktm) continue; // wave-uniform: waves 0/1 idle on the block's last tile

    floatx4 sf0[4], sf1[4];
#pragma unroll
    for (int nt = 0; nt < 4; nt++) {
      int r = nt * 16 + l15;
      int g0 = (quad ^ (r & 7)) * 8;
      bfx8 kf0 = *(const bfx8*)&Ks[r][g0];
      bfx8 kf1 = *(const bfx8*)&Ks[r][g0 ^ 32];
      floatx4 z0 = {0.f, 0.f, 0.f, 0.f}, z1 = {0.f, 0.f, 0.f, 0.f};
      z0 = __builtin_amdgcn_mfma_f32_16x16x32_bf16(kf0, qf0, z0, 0, 0, 0);
      sf0[nt] = __builtin_amdgcn_mfma_f32_16x16x32_bf16(kf1, qf1, z0, 0, 0, 0);
      z1 = __builtin_amdgcn_mfma_f32_16x16x32_bf16(kf0, qf2, z1, 0, 0, 0);
      sf1[nt] = __builtin_amdgcn_mfma_f32_16x16x32_bf16(kf1, qf3, z1, 0, 0, 0);
    }
    if (kt < ktm) {
      // interior tile: no causal masking (all kv strictly below all q rows)
#pragma unroll
      for (int nt = 0; nt < 4; nt++) {
        bfx4 pk0, pk1;
#pragma unroll
        for (int r = 0; r < 4; r++) {
          float p0 = exp2f(sf0[nt][r]);
          float p1 = exp2f(sf1[nt][r]);
          ps0 += p0; ps1 += p1;
          pk0[r] = (__bf16)p0; pk1[r] = (__bf16)p1;
        }
        *(bfx4*)&P[l15][nt * 16 + quad * 4] = pk0;
        *(bfx4*)&P[16 + l15][nt * 16 + quad * 4] = pk1;
      }
    } else {
      // diagonal tile
#pragma unroll
      for (int nt = 0; nt < 4; nt++) {
        bfx4 pk0, pk1;
#pragma unroll
        for (int r = 0; r < 4; r++) {
          int kvrel = nt * 16 + quad * 4 + r;
          float p0 = exp2f(sf0[nt][r]);
          float p1 = exp2f(sf1[nt][r]);
          p0 = (kvrel - l15 > dq0) ? 0.f : p0;
          p1 = (kvrel - l15 > dq1) ? 0.f : p1;
          ps0 += p0; ps1 += p1;
          pk0[r] = (__bf16)p0; pk1[r] = (__bf16)p1;
        }
        *(bfx4*)&P[l15][nt * 16 + quad * 4] = pk0;
        *(bfx4*)&P[16 + l15][nt * 16 + quad * 4] = pk1;
      }
    }
    bfx8 pa00 = *(const bfx8*)&P[l15][quad * 8];
    bfx8 pa01 = *(const bfx8*)&P[l15][32 + quad * 8];
    bfx8 pa10 = *(const bfx8*)&P[16 + l15][quad * 8];
    bfx8 pa11 = *(const bfx8*)&P[16 + l15][32 + quad * 8];
#pragma unroll
    for (int ot = 0; ot < 4; ot++) {
      int d = ot * 16 + l15;
      int g0 = (quad ^ (d & 7)) * 8;
      bfx8 vf0 = *(const bfx8*)&Vs[d][g0];
      bfx8 vf1 = *(const bfx8*)&Vs[d][g0 ^ 32];
      oacc0[ot] = __builtin_amdgcn_mfma_f32_16x16x32_bf16(pa00, vf0, oacc0[ot], 0, 0, 0);
      oacc0[ot] = __builtin_amdgcn_mfma_f32_16x16x32_bf16(pa01, vf1, oacc0[ot], 0, 0, 0);
      oacc1[ot] = __builtin_amdgcn_mfma_f32_16x16x32_bf16(pa10, vf0, oacc1[ot], 0, 0, 0);
      oacc1[ot] = __builtin_amdgcn_mfma_f32_16x16x32_bf16(pa11, vf1, oacc1[ot], 0, 0, 0);
    }
  }
  ps0 += __shfl_xor(ps0, 16);
  ps0 += __shfl_xor(ps0, 32);
  ps1 += __shfl_xor(ps1, 16);
  ps1 += __shfl_xor(ps1, 32);
  float rl0[4], rl1[4];
#pragma unroll
  for (int r = 0; r < 4; r++) {
    rl0[r] = 1.0f / __shfl(ps0, quad * 4 + r);
    rl1[r] = 1.0f / __shfl(ps1, quad * 4 + r);
  }
#pragma unroll
  for (int ot = 0; ot < 4; ot++)
#pragma unroll
    for (int r = 0; r < 4; r++) {
      float v0 = oacc0[ot][r] * rl0[r];
      float v1 = oacc1[ot][r] * rl1[r];
      size_t col = h * HD_ + ot * 16 + l15;
      Ob[((size_t)b * S_ + q0w + quad * 4 + r) * AP_ + col] = (__bf16)v0;
      Ob[((size_t)b * S_ + q0w + 16 + quad * 4 + r) * AP_ + col] = (__bf16)v1;
    }
}

extern "C" void kernel_launch(void* const* d_in, const int* in_sizes, int n_in,
                              void* d_out, int out_size, void* d_ws, size_t ws_size,
                              hipStream_t stream) {
  const float* x   = (const float*)d_in[0];
  const float* cosT = (const float*)d_in[1];
  const float* sinT = (const float*)d_in[2];
  const float* wq  = (const float*)d_in[3];
  const float* wk  = (const float*)d_in[4];
  const float* wv  = (const float*)d_in[5];
  const float* wo  = (const float*)d_in[6];
  const float* qw  = (const float*)d_in[7];
  const float* kw  = (const float*)d_in[8];
  float* out = (float*)d_out;

  char* w = (char*)d_ws;
  // Lifetime-packed workspace:
  //   xbf [0, 17,301,504)  dead after gemm1; Qb/Kb/VTb reuse it (written by norm_rope)
  __bf16* xbf   = (__bf16*)(w);                        // 4096*2112*2 = 17,301,504
  __bf16* Qb    = (__bf16*)(w);                        //  8,388,608 (aliases dead xbf)
  __bf16* Kb    = (__bf16*)(w + 8388608);              //  2,097,152
  __bf16* VTb   = (__bf16*)(w + 10485760);             //  2*4*64*2112*2 = 2,162,688 (end 12,648,448)
  __bf16* wqkvT = (__bf16*)(w + 17301504);             // 1536*2112*2 = 6,488,064
  __bf16* woT   = (__bf16*)(w + 23789568);             // 2048*1088*2 = 4,456,448
  float*  qkv   = (float*) (w + 28246016);             // 2 splits * 4096*1536*4 = 50,331,648
  __bf16* attnO = (__bf16*)(w + 28246016);             // aliases qkv (dead after norm_rope)
                                                       // total end = 78,577,664

  // fused prep: cast (4096 blocks) + wq/wk/wv/wo transposes (2048+512+512+2048)
  prep_kernel<<<M_ + 5120, 256, 0, stream>>>(x, wq, wk, wv, wo, xbf, wqkvT, woT);
  // QKV GEMM, 256x128 tile, split-K=2: grid 12 x 16 x 2 = 384 blocks
  gemm_bf16_f32<<<dim3(NQKV_ / 128, M_ / 256, 2), 512, 0, stream>>>(
      xbf, wqkvT, qkv, M_, NQKV_, H_ / 2, XP_, XP_, NQKV_, (unsigned long long)QKV_ELEMS_);
  norm_rope_kernel<<<dim3(S_, B_), 256, 0, stream>>>(qkv, cosT, sinT, qw, kw, Qb, Kb, VTb);
  // attention: QBLK=128, 4 waves x 32 q-rows, grid 16 x 16 x 2 = 512 blocks
  attn_kernel<<<dim3(S_ / 128, NH_, B_), 256, 0, stream>>>(Qb, Kb, VTb, attnO);
  // output GEMM, 256x128 tile: grid 16 x 16 = 256 blocks
  gemm_bf16_f32<<<dim3(H_ / 128, M_ / 256, 1), 512, 0, stream>>>(
      attnO, woT, out, M_, H_, HQ_, AP_, AP_, H_, 0ull);
}

// Round 7
// 218.673 us; speedup vs baseline: 1.0330x; 1.0306x over previous
//
#include <hip/hip_runtime.h>

typedef float floatx4 __attribute__((ext_vector_type(4)));
typedef __bf16 bfx8 __attribute__((ext_vector_type(8)));
typedef __bf16 bfx4 __attribute__((ext_vector_type(4)));

// Problem constants
constexpr int B_ = 2, S_ = 2048, H_ = 2048, NH_ = 16, NKV_ = 4, HD_ = 64;
constexpr int M_ = B_ * S_;               // 4096 rows
constexpr int NQKV_ = NH_ * HD_ + 2 * NKV_ * HD_; // 1536
constexpr int HQ_ = NH_ * HD_;            // 1024
// Pitches: 128B-aligned (no cache-line straddle on 128B DMA row-chunks) AND an
// odd multiple of 64 elements (33x128B / 17x128B) to keep channel spread.
constexpr int XP_ = 2112;  // xbf / wqkvT pitch (4224B = 33*128)
constexpr int AP_ = 1088;  // attn-out / woT pitch (2176B = 17*128)
constexpr int VP_ = 2112;  // V-transposed pitch

#define GLB(p) ((const __attribute__((address_space(1))) void*)(p))
#define LDS(p) ((__attribute__((address_space(3))) void*)(p))

// ---------------- fused prep: fp32->bf16 cast of x  +  all 4 weight transposes ----------
__global__ __launch_bounds__(256) void prep_kernel(const float* __restrict__ x,
                                                   const float* __restrict__ wq,
                                                   const float* __restrict__ wk,
                                                   const float* __restrict__ wv,
                                                   const float* __restrict__ wo,
                                                   __bf16* __restrict__ xbf,
                                                   __bf16* __restrict__ wqkvT,
                                                   __bf16* __restrict__ woT) {
  __shared__ float tile[32][33];
  int bid = blockIdx.x;
  if (bid < M_) {
    // ---- cast branch ----
    const float4* s = (const float4*)(x + (size_t)bid * H_);
    __bf16* d = xbf + (size_t)bid * XP_;
#pragma unroll
    for (int i = 0; i < 2; i++) {
      int c = i * 256 + threadIdx.x;
      float4 v = s[c];
      bfx4 o;
      o[0] = (__bf16)v.x; o[1] = (__bf16)v.y; o[2] = (__bf16)v.z; o[3] = (__bf16)v.w;
      *(bfx4*)(d + c * 4) = o;
    }
    return;
  }
  bid -= M_;
  const float* src; __bf16* dst; int N, dstOff, pitch, nbx;
  if (bid < 2048)      { src = wq; dst = wqkvT; N = 1024; dstOff = 0;    pitch = XP_; nbx = 32; }
  else if (bid < 2560) { bid -= 2048; src = wk; dst = wqkvT; N = 256; dstOff = 1024; pitch = XP_; nbx = 8; }
  else if (bid < 3072) { bid -= 2560; src = wv; dst = wqkvT; N = 256; dstOff = 1280; pitch = XP_; nbx = 8; }
  else                 { bid -= 3072; src = wo; dst = woT;   N = 2048; dstOff = 0;   pitch = AP_; nbx = 64; }
  int n0 = (bid % nbx) * 32, k0 = (bid / nbx) * 32;
  int tx = threadIdx.x & 31, ty = threadIdx.x >> 5; // (32,8) layout
#pragma unroll
  for (int r = 0; r < 32; r += 8)
    tile[ty + r][tx] = src[(size_t)(k0 + ty + r) * N + n0 + tx];
  __syncthreads();
#pragma unroll
  for (int r = 0; r < 32; r += 8)
    dst[(size_t)(n0 + ty + r + dstOff) * pitch + k0 + tx] = (__bf16)tile[tx][ty + r];
}

// ---------------- fused QKV GEMM + RMSNorm + RoPE + attention-layout epilogue -----------
// 128x128 tile, BK=64, 4 waves (2x2). Each wave's N-range is 64 cols = EXACTLY one head,
// so the epilogue is block-local: RMSNorm sum spans ni x l15 (4 regs x 16 lanes, shuffle-
// reduce), RoPE partner d^32 = acc[mi][ni^2] (same lane), cos/sin loaded per row.
// Eliminates the fp32 qkv intermediate (100 MB of HBM with split-K) and the norm_rope
// kernel. R1 showed this GEMM structure is staging-rate-bound, not occupancy-bound, so
// 384 blocks (1.5/CU) is fine; R4's pitch alignment doubled the staging rate.
__global__ __launch_bounds__(256) void gemm_qkv_fused(const __bf16* __restrict__ A,
                                                      const __bf16* __restrict__ Bt,
                                                      const float* __restrict__ cosT,
                                                      const float* __restrict__ sinT,
                                                      const float* __restrict__ qw,
                                                      const float* __restrict__ kw,
                                                      __bf16* __restrict__ Qo,
                                                      __bf16* __restrict__ Ko,
                                                      __bf16* __restrict__ VTo) {
  __shared__ __align__(16) __bf16 As[128 * 64];
  __shared__ __align__(16) __bf16 Bs[128 * 64];
  int wid = threadIdx.x >> 6, lane = threadIdx.x & 63;
  int l15 = lane & 15, quad = lane >> 4;
  int wm = (wid >> 1) * 64, wn = (wid & 1) * 64;
  int m0 = blockIdx.y * 128, n0 = blockIdx.x * 128;
  int srow_off = lane >> 3;
  int gphys = lane & 7;
  floatx4 acc[4][4] = {};
  for (int kb = 0; kb < H_; kb += 64) {
#pragma unroll
    for (int j = 0; j < 4; j++) {
      int rbase = wid * 32 + j * 8;
      int row = rbase + srow_off;
      int glog = gphys ^ (row & 7);
      const __bf16* ga = &A[(size_t)(m0 + row) * XP_ + kb + glog * 8];
      const __bf16* gb = &Bt[(size_t)(n0 + row) * XP_ + kb + glog * 8];
      __builtin_amdgcn_global_load_lds(GLB(ga), LDS(&As[rbase * 64]), 16, 0, 0);
      __builtin_amdgcn_global_load_lds(GLB(gb), LDS(&Bs[rbase * 64]), 16, 0, 0);
    }
    __syncthreads();
#pragma unroll
    for (int kk = 0; kk < 64; kk += 32) {
      int cgq = (kk >> 3) + quad;
      bfx8 af[4], bfr[4];
#pragma unroll
      for (int mi = 0; mi < 4; mi++) {
        int row = wm + mi * 16 + l15;
        af[mi] = *(const bfx8*)&As[row * 64 + (cgq ^ (row & 7)) * 8];
      }
#pragma unroll
      for (int ni = 0; ni < 4; ni++) {
        int row = wn + ni * 16 + l15;
        bfr[ni] = *(const bfx8*)&Bs[row * 64 + (cgq ^ (row & 7)) * 8];
      }
#pragma unroll
      for (int mi = 0; mi < 4; mi++)
#pragma unroll
        for (int ni = 0; ni < 4; ni++)
          acc[mi][ni] = __builtin_amdgcn_mfma_f32_16x16x32_bf16(af[mi], bfr[ni], acc[mi][ni], 0, 0, 0);
    }
    __syncthreads();
  }
  // ---------------- fused epilogue ----------------
  // acc[mi][ni][r] = C[m0+wm+mi*16+quad*4+r][n0+wn+ni*16+l15]
  int hh = (n0 + wn) >> 6;   // wave-uniform head id: 0..15 q, 16..19 k, 20..23 v
  int b = m0 >> 11;          // whole block within one batch (m0 mult of 128)
  if (hh < 20) {
    const float* wptr = (hh < 16) ? qw : kw;
    float wv4[4];
#pragma unroll
    for (int ni = 0; ni < 4; ni++) wv4[ni] = wptr[ni * 16 + l15];
    __bf16* outp = (hh < 16) ? (Qo + (((size_t)b * NH_ + hh) * S_) * HD_)
                             : (Ko + (((size_t)b * NKV_ + (hh - 16)) * S_) * HD_);
#pragma unroll
    for (int mi = 0; mi < 4; mi++) {
#pragma unroll
      for (int r = 0; r < 4; r++) {
        // RMSNorm: sum of squares over the head's 64 cols (4 regs x 16 lanes)
        float ssum = acc[mi][0][r] * acc[mi][0][r] + acc[mi][1][r] * acc[mi][1][r] +
                     acc[mi][2][r] * acc[mi][2][r] + acc[mi][3][r] * acc[mi][3][r];
        ssum += __shfl_xor(ssum, 1);
        ssum += __shfl_xor(ssum, 2);
        ssum += __shfl_xor(ssum, 4);
        ssum += __shfl_xor(ssum, 8);
        float rs = rsqrtf(ssum * (1.0f / 64.0f) + 1e-6f);
        int row = wm + mi * 16 + quad * 4 + r;       // row within block
        int s = (m0 & 2047) + row;                   // sequence position
        float nv[4];
#pragma unroll
        for (int ni = 0; ni < 4; ni++) nv[ni] = acc[mi][ni][r] * rs * wv4[ni];
#pragma unroll
        for (int ni = 0; ni < 4; ni++) {
          int d = ni * 16 + l15;
          float c = cosT[s * HD_ + d];
          float sn = sinT[s * HD_ + d];
          float partner = nv[ni ^ 2];                // d^32 lives in ni^2, same lane
          float rot = (ni < 2) ? -partner : partner; // rotate_half sign
          outp[(size_t)s * HD_ + d] = (__bf16)(nv[ni] * c + rot * sn);
        }
      }
    }
  } else {
    // V head: transpose-store (same scatter pattern norm_rope used)
    __bf16* vtp = VTo + ((size_t)b * NKV_ + (hh - 20)) * (size_t)HD_ * VP_;
#pragma unroll
    for (int mi = 0; mi < 4; mi++)
#pragma unroll
      for (int r = 0; r < 4; r++) {
        int row = wm + mi * 16 + quad * 4 + r;
        int s = (m0 & 2047) + row;
#pragma unroll
        for (int ni = 0; ni < 4; ni++) {
          int d = ni * 16 + l15;
          vtp[(size_t)d * VP_ + s] = (__bf16)acc[mi][ni][r];
        }
      }
  }
}

// ---------------- bf16 MFMA GEMM: 256x128 tile, BK=64, 8 waves (4m x 2n) ------------
// (used for the output projection only)
__global__ __launch_bounds__(512) void gemm_bf16_f32(const __bf16* __restrict__ A,
                                                     const __bf16* __restrict__ Bt,
                                                     float* __restrict__ C,
                                                     int M, int N, int K,
                                                     int lda, int ldb, int ldc) {
  __shared__ __align__(16) __bf16 As[256 * 64];
  __shared__ __align__(16) __bf16 Bs[128 * 64];
  int wid = threadIdx.x >> 6, lane = threadIdx.x & 63;
  int l15 = lane & 15, quad = lane >> 4;
  int wm = (wid >> 1) * 64, wn = (wid & 1) * 64; // 4m x 2n wave grid
  int m0 = blockIdx.y * 256, n0 = blockIdx.x * 128;
  int srow_off = lane >> 3;
  int gphys = lane & 7;
  floatx4 acc[4][4] = {};
  for (int kb = 0; kb < K; kb += 64) {
#pragma unroll
    for (int j = 0; j < 4; j++) {
      int rbase = j * 64 + wid * 8;
      int row = rbase + srow_off;
      int glog = gphys ^ (row & 7);
      const __bf16* ga = &A[(size_t)(m0 + row) * lda + kb + glog * 8];
      __builtin_amdgcn_global_load_lds(GLB(ga), LDS(&As[rbase * 64]), 16, 0, 0);
    }
#pragma unroll
    for (int j = 0; j < 2; j++) {
      int rbase = j * 64 + wid * 8;
      int row = rbase + srow_off;
      int glog = gphys ^ (row & 7);
      const __bf16* gb = &Bt[(size_t)(n0 + row) * ldb + kb + glog * 8];
      __builtin_amdgcn_global_load_lds(GLB(gb), LDS(&Bs[rbase * 64]), 16, 0, 0);
    }
    __syncthreads(); // compiler emits vmcnt(0) drain before barrier
#pragma unroll
    for (int kk = 0; kk < 64; kk += 32) {
      int cgq = (kk >> 3) + quad;
      bfx8 af[4], bfr[4];
#pragma unroll
      for (int mi = 0; mi < 4; mi++) {
        int row = wm + mi * 16 + l15;
        af[mi] = *(const bfx8*)&As[row * 64 + (cgq ^ (row & 7)) * 8];
      }
#pragma unroll
      for (int ni = 0; ni < 4; ni++) {
        int row = wn + ni * 16 + l15;
        bfr[ni] = *(const bfx8*)&Bs[row * 64 + (cgq ^ (row & 7)) * 8];
      }
#pragma unroll
      for (int mi = 0; mi < 4; mi++)
#pragma unroll
        for (int ni = 0; ni < 4; ni++)
          acc[mi][ni] = __builtin_amdgcn_mfma_f32_16x16x32_bf16(af[mi], bfr[ni], acc[mi][ni], 0, 0, 0);
    }
    __syncthreads();
  }
#pragma unroll
  for (int mi = 0; mi < 4; mi++)
#pragma unroll
    for (int ni = 0; ni < 4; ni++) {
      int row = m0 + wm + mi * 16 + quad * 4;
      int coln = n0 + wn + ni * 16 + l15;
#pragma unroll
      for (int r = 0; r < 4; r++)
        C[(size_t)(row + r) * ldc + coln] = acc[mi][ni][r];
    }
}

// ---------------- flash attention (causal, GQA), block-cooperative LDS staging ----------
// EXACT round-4 version (best measured: 45.0us) — 4 waves, QBLK=64, reg-staged dbuf.
__global__ __launch_bounds__(256, 4) void attn_kernel(const __bf16* __restrict__ Q,
                                                      const __bf16* __restrict__ Kc,
                                                      const __bf16* __restrict__ VT,
                                                      __bf16* __restrict__ Ob) {
  int px = blockIdx.x, h = blockIdx.y, b = blockIdx.z;
  int u = (px + 2 * (h & 7)) & 31;
  int qt = (((h >> 3) ^ b) & 1) ? (31 - u) : u;
  int wid = threadIdx.x >> 6, lane = threadIdx.x & 63;
  int l15 = lane & 15, quad = lane >> 4;
  int q0 = qt * 64 + wid * 16;
  int kvh = h >> 2; // N_REP = 4
  const __bf16* Qh = Q + (((size_t)b * NH_ + h) * S_ + q0) * HD_;
  const __bf16* Kh = Kc + ((size_t)b * NKV_ + kvh) * S_ * HD_;
  const __bf16* Vh = VT + ((size_t)b * NKV_ + kvh) * (size_t)HD_ * VP_;
  __shared__ __align__(16) __bf16 Ks[64][72]; // [kv][hd]
  __shared__ __align__(16) __bf16 Vs[64][72]; // [hd][kv]
  __shared__ __align__(16) __bf16 Pst[4][16][72];
  __bf16 (*P)[72] = Pst[wid];

  int srow = threadIdx.x >> 3;         // 0..31
  int scol = (threadIdx.x & 7) * 8;    // element offset 0..56

  bfx8 qf0, qf1;
  {
    const __bf16* qp = Qh + l15 * HD_ + quad * 8;
    qf0 = *(const bfx8*)qp;
    qf1 = *(const bfx8*)(qp + 32);
  }
  floatx4 oacc[4] = {};
  float ps = 0.f;
  int ntiles = qt + 1; // causal, block-uniform
  bfx8 kpre0, kpre1, vpre0, vpre1;
  kpre0 = *(const bfx8*)&Kh[(size_t)srow * HD_ + scol];
  kpre1 = *(const bfx8*)&Kh[(size_t)(srow + 32) * HD_ + scol];
  vpre0 = *(const bfx8*)&Vh[(size_t)srow * VP_ + scol];
  vpre1 = *(const bfx8*)&Vh[(size_t)(srow + 32) * VP_ + scol];
  for (int kt = 0; kt < ntiles; kt++) {
    int kv0 = kt * 64;
    int dq = q0 - kv0;
    __syncthreads();
    *(bfx8*)&Ks[srow][scol] = kpre0;
    *(bfx8*)&Ks[srow + 32][scol] = kpre1;
    *(bfx8*)&Vs[srow][scol] = vpre0;
    *(bfx8*)&Vs[srow + 32][scol] = vpre1;
    __syncthreads();
    if (kt + 1 < ntiles) {
      int kn = kv0 + 64;
      kpre0 = *(const bfx8*)&Kh[(size_t)(kn + srow) * HD_ + scol];
      kpre1 = *(const bfx8*)&Kh[(size_t)(kn + srow + 32) * HD_ + scol];
      vpre0 = *(const bfx8*)&Vh[(size_t)srow * VP_ + kn + scol];
      vpre1 = *(const bfx8*)&Vh[(size_t)(srow + 32) * VP_ + kn + scol];
    }
    floatx4 sf[4];
#pragma unroll
    for (int nt = 0; nt < 4; nt++) {
      bfx8 kf0 = *(const bfx8*)&Ks[nt * 16 + l15][quad * 8];
      bfx8 kf1 = *(const bfx8*)&Ks[nt * 16 + l15][32 + quad * 8];
      floatx4 z = {0.f, 0.f, 0.f, 0.f};
      z = __builtin_amdgcn_mfma_f32_16x16x32_bf16(kf0, qf0, z, 0, 0, 0);
      sf[nt] = __builtin_amdgcn_mfma_f32_16x16x32_bf16(kf1, qf1, z, 0, 0, 0);
    }
#pragma unroll
    for (int nt = 0; nt < 4; nt++) {
      bfx4 pk;
#pragma unroll
      for (int r = 0; r < 4; r++) {
        int kvrel = nt * 16 + quad * 4 + r;
        float p = __expf(sf[nt][r] * 0.125f);
        p = (kvrel - l15 > dq) ? 0.f : p;
        ps += p;
        pk[r] = (__bf16)p;
      }
      *(bfx4*)&P[l15][nt * 16 + quad * 4] = pk;
    }
    bfx8 pa0 = *(const bfx8*)&P[l15][quad * 8];
    bfx8 pa1 = *(const bfx8*)&P[l15][32 + quad * 8];
#pragma unroll
    for (int ot = 0; ot < 4; ot++) {
      bfx8 vf0 = *(const bfx8*)&Vs[ot * 16 + l15][quad * 8];
      bfx8 vf1 = *(const bfx8*)&Vs[ot * 16 + l15][32 + quad * 8];
      oacc[ot] = __builtin_amdgcn_mfma_f32_16x16x32_bf16(pa0, vf0, oacc[ot], 0, 0, 0);
      oacc[ot] = __builtin_amdgcn_mfma_f32_16x16x32_bf16(pa1, vf1, oacc[ot], 0, 0, 0);
    }
  }
  ps += __shfl_xor(ps, 16);
  ps += __shfl_xor(ps, 32);
  float rl[4];
#pragma unroll
  for (int r = 0; r < 4; r++) rl[r] = 1.0f / __shfl(ps, quad * 4 + r);
#pragma unroll
  for (int ot = 0; ot < 4; ot++)
#pragma unroll
    for (int r = 0; r < 4; r++) {
      float val = oacc[ot][r] * rl[r];
      Ob[((size_t)b * S_ + q0 + quad * 4 + r) * AP_ + h * HD_ + ot * 16 + l15] = (__bf16)val;
    }
}

extern "C" void kernel_launch(void* const* d_in, const int* in_sizes, int n_in,
                              void* d_out, int out_size, void* d_ws, size_t ws_size,
                              hipStream_t stream) {
  const float* x   = (const float*)d_in[0];
  const float* cosT = (const float*)d_in[1];
  const float* sinT = (const float*)d_in[2];
  const float* wq  = (const float*)d_in[3];
  const float* wk  = (const float*)d_in[4];
  const float* wv  = (const float*)d_in[5];
  const float* wo  = (const float*)d_in[6];
  const float* qw  = (const float*)d_in[7];
  const float* kw  = (const float*)d_in[8];
  float* out = (float*)d_out;

  char* w = (char*)d_ws;
  // NOTE: Qb/Kb/VTb may NOT alias xbf anymore — gemm_qkv_fused reads xbf while
  // writing them. Straight-line layout (total ~49.8 MB):
  __bf16* xbf   = (__bf16*)(w);                        // 4096*2112*2 = 17,301,504
  __bf16* wqkvT = (__bf16*)(w + 17301504);             // 1536*2112*2 =  6,488,064
  __bf16* woT   = (__bf16*)(w + 23789568);             // 2048*1088*2 =  4,456,448
  __bf16* Qb    = (__bf16*)(w + 28246016);             //  8,388,608
  __bf16* Kb    = (__bf16*)(w + 36634624);             //  2,097,152
  __bf16* VTb   = (__bf16*)(w + 38731776);             // 2*4*64*2112*2 = 2,162,688
  __bf16* attnO = (__bf16*)(w + 40894464);             // 4096*1088*2 = 8,912,896 (end 49,807,360)

  // fused prep: cast (4096 blocks) + wq/wk/wv/wo transposes (2048+512+512+2048)
  prep_kernel<<<M_ + 5120, 256, 0, stream>>>(x, wq, wk, wv, wo, xbf, wqkvT, woT);
  // QKV GEMM with fused RMSNorm+RoPE+layout epilogue: 128x128, grid 12 x 32 = 384 blocks
  gemm_qkv_fused<<<dim3(NQKV_ / 128, M_ / 128), 256, 0, stream>>>(
      xbf, wqkvT, cosT, sinT, qw, kw, Qb, Kb, VTb);
  // attention: QBLK=64, 4 waves, grid 32 x 16 x 2 = 1024 blocks (round-4 exact)
  attn_kernel<<<dim3(32, NH_, B_), 256, 0, stream>>>(Qb, Kb, VTb, attnO);
  // output GEMM, 256x128 tile: grid 16 x 16 = 256 blocks
  gemm_bf16_f32<<<dim3(H_ / 128, M_ / 256), 512, 0, stream>>>(
      attnO, woT, out, M_, H_, HQ_, AP_, AP_, H_);
}

// Round 8
// 215.915 us; speedup vs baseline: 1.0462x; 1.0128x over previous
//
#include <hip/hip_runtime.h>

typedef float floatx4 __attribute__((ext_vector_type(4)));
typedef __bf16 bfx8 __attribute__((ext_vector_type(8)));
typedef __bf16 bfx4 __attribute__((ext_vector_type(4)));

// Problem constants
constexpr int B_ = 2, S_ = 2048, H_ = 2048, NH_ = 16, NKV_ = 4, HD_ = 64;
constexpr int M_ = B_ * S_;               // 4096 rows
constexpr int NQKV_ = NH_ * HD_ + 2 * NKV_ * HD_; // 1536
constexpr int HQ_ = NH_ * HD_;            // 1024
// Pitches: 128B-aligned (no cache-line straddle on 128B DMA row-chunks) AND an
// odd multiple of 64 elements (33x128B / 17x128B) to keep channel spread.
constexpr int XP_ = 2112;  // xbf / wqkvT pitch (4224B = 33*128)
constexpr int AP_ = 1088;  // attn-out / woT pitch (2176B = 17*128)
constexpr int VP_ = 2112;  // V-transposed pitch

#define GLB(p) ((const __attribute__((address_space(1))) void*)(p))
#define LDS(p) ((__attribute__((address_space(3))) void*)(p))

// ---------------- fused prep: fp32->bf16 cast of x  +  all 4 weight transposes ----------
__global__ __launch_bounds__(256) void prep_kernel(const float* __restrict__ x,
                                                   const float* __restrict__ wq,
                                                   const float* __restrict__ wk,
                                                   const float* __restrict__ wv,
                                                   const float* __restrict__ wo,
                                                   __bf16* __restrict__ xbf,
                                                   __bf16* __restrict__ wqkvT,
                                                   __bf16* __restrict__ woT) {
  __shared__ float tile[32][33];
  int bid = blockIdx.x;
  if (bid < M_) {
    // ---- cast branch ----
    const float4* s = (const float4*)(x + (size_t)bid * H_);
    __bf16* d = xbf + (size_t)bid * XP_;
#pragma unroll
    for (int i = 0; i < 2; i++) {
      int c = i * 256 + threadIdx.x;
      float4 v = s[c];
      bfx4 o;
      o[0] = (__bf16)v.x; o[1] = (__bf16)v.y; o[2] = (__bf16)v.z; o[3] = (__bf16)v.w;
      *(bfx4*)(d + c * 4) = o;
    }
    return;
  }
  bid -= M_;
  const float* src; __bf16* dst; int N, dstOff, pitch, nbx;
  if (bid < 2048)      { src = wq; dst = wqkvT; N = 1024; dstOff = 0;    pitch = XP_; nbx = 32; }
  else if (bid < 2560) { bid -= 2048; src = wk; dst = wqkvT; N = 256; dstOff = 1024; pitch = XP_; nbx = 8; }
  else if (bid < 3072) { bid -= 2560; src = wv; dst = wqkvT; N = 256; dstOff = 1280; pitch = XP_; nbx = 8; }
  else                 { bid -= 3072; src = wo; dst = woT;   N = 2048; dstOff = 0;   pitch = AP_; nbx = 64; }
  int n0 = (bid % nbx) * 32, k0 = (bid / nbx) * 32;
  int tx = threadIdx.x & 31, ty = threadIdx.x >> 5; // (32,8) layout
#pragma unroll
  for (int r = 0; r < 32; r += 8)
    tile[ty + r][tx] = src[(size_t)(k0 + ty + r) * N + n0 + tx];
  __syncthreads();
#pragma unroll
  for (int r = 0; r < 32; r += 8)
    dst[(size_t)(n0 + ty + r + dstOff) * pitch + k0 + tx] = (__bf16)tile[tx][ty + r];
}

// ---------------- fused QKV GEMM + RMSNorm + RoPE + attention-layout epilogue -----------
// 128x128 tile, BK=64, 4 waves (2x2), explicit 2-phase LDS DOUBLE-BUFFER:
// per K-step { issue DMA for t+1 into buf^1; ds_read+MFMA from buf; __syncthreads }.
// The compiler's vmcnt(0)-before-barrier then only drains what's LEFT of the prefetch
// after compute — period ~ max(stage, compute) instead of stage+compute. At 1.5
// blocks/CU there is no cross-block overlap to hide the drain (m99's neutral result was
// at 3-4 blocks/CU), so the overlap must come from within the block.
__global__ __launch_bounds__(256) void gemm_qkv_fused(const __bf16* __restrict__ A,
                                                      const __bf16* __restrict__ Bt,
                                                      const float* __restrict__ cosT,
                                                      const float* __restrict__ sinT,
                                                      const float* __restrict__ qw,
                                                      const float* __restrict__ kw,
                                                      __bf16* __restrict__ Qo,
                                                      __bf16* __restrict__ Ko,
                                                      __bf16* __restrict__ VTo) {
  __shared__ __align__(16) __bf16 As[2][128 * 64];
  __shared__ __align__(16) __bf16 Bs[2][128 * 64];
  int wid = threadIdx.x >> 6, lane = threadIdx.x & 63;
  int l15 = lane & 15, quad = lane >> 4;
  int wm = (wid >> 1) * 64, wn = (wid & 1) * 64;
  int m0 = blockIdx.y * 128, n0 = blockIdx.x * 128;
  int srow_off = lane >> 3;
  int gphys = lane & 7;
  floatx4 acc[4][4] = {};

  // ---- staging helper (issue only; no wait) ----
  auto stage = [&](int bufi, int kb) {
#pragma unroll
    for (int j = 0; j < 4; j++) {
      int rbase = wid * 32 + j * 8;
      int row = rbase + srow_off;
      int glog = gphys ^ (row & 7);
      const __bf16* ga = &A[(size_t)(m0 + row) * XP_ + kb + glog * 8];
      const __bf16* gb = &Bt[(size_t)(n0 + row) * XP_ + kb + glog * 8];
      __builtin_amdgcn_global_load_lds(GLB(ga), LDS(&As[bufi][rbase * 64]), 16, 0, 0);
      __builtin_amdgcn_global_load_lds(GLB(gb), LDS(&Bs[bufi][rbase * 64]), 16, 0, 0);
    }
  };

  stage(0, 0);
  __syncthreads(); // buf0 ready
  int buf = 0;
  for (int kb = 0; kb < H_; kb += 64) {
    if (kb + 64 < H_) stage(buf ^ 1, kb + 64); // prefetch next tile (overlaps compute)
#pragma unroll
    for (int kk = 0; kk < 64; kk += 32) {
      int cgq = (kk >> 3) + quad;
      bfx8 af[4], bfr[4];
#pragma unroll
      for (int mi = 0; mi < 4; mi++) {
        int row = wm + mi * 16 + l15;
        af[mi] = *(const bfx8*)&As[buf][row * 64 + (cgq ^ (row & 7)) * 8];
      }
#pragma unroll
      for (int ni = 0; ni < 4; ni++) {
        int row = wn + ni * 16 + l15;
        bfr[ni] = *(const bfx8*)&Bs[buf][row * 64 + (cgq ^ (row & 7)) * 8];
      }
#pragma unroll
      for (int mi = 0; mi < 4; mi++)
#pragma unroll
        for (int ni = 0; ni < 4; ni++)
          acc[mi][ni] = __builtin_amdgcn_mfma_f32_16x16x32_bf16(af[mi], bfr[ni], acc[mi][ni], 0, 0, 0);
    }
    __syncthreads(); // drains remaining prefetch + protects buf overwrite next iter
    buf ^= 1;
  }
  // ---------------- fused epilogue ----------------
  // acc[mi][ni][r] = C[m0+wm+mi*16+quad*4+r][n0+wn+ni*16+l15]
  int hh = (n0 + wn) >> 6;   // wave-uniform head id: 0..15 q, 16..19 k, 20..23 v
  int b = m0 >> 11;          // whole block within one batch (m0 mult of 128)
  if (hh < 20) {
    const float* wptr = (hh < 16) ? qw : kw;
    float wv4[4];
#pragma unroll
    for (int ni = 0; ni < 4; ni++) wv4[ni] = wptr[ni * 16 + l15];
    __bf16* outp = (hh < 16) ? (Qo + (((size_t)b * NH_ + hh) * S_) * HD_)
                             : (Ko + (((size_t)b * NKV_ + (hh - 16)) * S_) * HD_);
#pragma unroll
    for (int mi = 0; mi < 4; mi++) {
#pragma unroll
      for (int r = 0; r < 4; r++) {
        // RMSNorm: sum of squares over the head's 64 cols (4 regs x 16 lanes)
        float ssum = acc[mi][0][r] * acc[mi][0][r] + acc[mi][1][r] * acc[mi][1][r] +
                     acc[mi][2][r] * acc[mi][2][r] + acc[mi][3][r] * acc[mi][3][r];
        ssum += __shfl_xor(ssum, 1);
        ssum += __shfl_xor(ssum, 2);
        ssum += __shfl_xor(ssum, 4);
        ssum += __shfl_xor(ssum, 8);
        float rs = rsqrtf(ssum * (1.0f / 64.0f) + 1e-6f);
        int row = wm + mi * 16 + quad * 4 + r;       // row within block
        int s = (m0 & 2047) + row;                   // sequence position
        float nv[4];
#pragma unroll
        for (int ni = 0; ni < 4; ni++) nv[ni] = acc[mi][ni][r] * rs * wv4[ni];
#pragma unroll
        for (int ni = 0; ni < 4; ni++) {
          int d = ni * 16 + l15;
          float c = cosT[s * HD_ + d];
          float sn = sinT[s * HD_ + d];
          float partner = nv[ni ^ 2];                // d^32 lives in ni^2, same lane
          float rot = (ni < 2) ? -partner : partner; // rotate_half sign
          outp[(size_t)s * HD_ + d] = (__bf16)(nv[ni] * c + rot * sn);
        }
      }
    }
  } else {
    // V head: transpose-store (same scatter pattern norm_rope used)
    __bf16* vtp = VTo + ((size_t)b * NKV_ + (hh - 20)) * (size_t)HD_ * VP_;
#pragma unroll
    for (int mi = 0; mi < 4; mi++)
#pragma unroll
      for (int r = 0; r < 4; r++) {
        int row = wm + mi * 16 + quad * 4 + r;
        int s = (m0 & 2047) + row;
#pragma unroll
        for (int ni = 0; ni < 4; ni++) {
          int d = ni * 16 + l15;
          vtp[(size_t)d * VP_ + s] = (__bf16)acc[mi][ni][r];
        }
      }
  }
}

// ---------------- bf16 MFMA GEMM: 256x128 tile, BK=64, 8 waves, 2-phase dbuf -----------
// (used for the output projection only; grid 256 = 1 block/CU -> the naked-drain regime)
__global__ __launch_bounds__(512) void gemm_bf16_f32(const __bf16* __restrict__ A,
                                                     const __bf16* __restrict__ Bt,
                                                     float* __restrict__ C,
                                                     int M, int N, int K,
                                                     int lda, int ldb, int ldc) {
  __shared__ __align__(16) __bf16 As[2][256 * 64];
  __shared__ __align__(16) __bf16 Bs[2][128 * 64];
  int wid = threadIdx.x >> 6, lane = threadIdx.x & 63;
  int l15 = lane & 15, quad = lane >> 4;
  int wm = (wid >> 1) * 64, wn = (wid & 1) * 64; // 4m x 2n wave grid
  int m0 = blockIdx.y * 256, n0 = blockIdx.x * 128;
  int srow_off = lane >> 3;
  int gphys = lane & 7;
  floatx4 acc[4][4] = {};

  auto stage = [&](int bufi, int kb) {
#pragma unroll
    for (int j = 0; j < 4; j++) {
      int rbase = j * 64 + wid * 8;
      int row = rbase + srow_off;
      int glog = gphys ^ (row & 7);
      const __bf16* ga = &A[(size_t)(m0 + row) * lda + kb + glog * 8];
      __builtin_amdgcn_global_load_lds(GLB(ga), LDS(&As[bufi][rbase * 64]), 16, 0, 0);
    }
#pragma unroll
    for (int j = 0; j < 2; j++) {
      int rbase = j * 64 + wid * 8;
      int row = rbase + srow_off;
      int glog = gphys ^ (row & 7);
      const __bf16* gb = &Bt[(size_t)(n0 + row) * ldb + kb + glog * 8];
      __builtin_amdgcn_global_load_lds(GLB(gb), LDS(&Bs[bufi][rbase * 64]), 16, 0, 0);
    }
  };

  stage(0, 0);
  __syncthreads();
  int buf = 0;
  for (int kb = 0; kb < K; kb += 64) {
    if (kb + 64 < K) stage(buf ^ 1, kb + 64);
#pragma unroll
    for (int kk = 0; kk < 64; kk += 32) {
      int cgq = (kk >> 3) + quad;
      bfx8 af[4], bfr[4];
#pragma unroll
      for (int mi = 0; mi < 4; mi++) {
        int row = wm + mi * 16 + l15;
        af[mi] = *(const bfx8*)&As[buf][row * 64 + (cgq ^ (row & 7)) * 8];
      }
#pragma unroll
      for (int ni = 0; ni < 4; ni++) {
        int row = wn + ni * 16 + l15;
        bfr[ni] = *(const bfx8*)&Bs[buf][row * 64 + (cgq ^ (row & 7)) * 8];
      }
#pragma unroll
      for (int mi = 0; mi < 4; mi++)
#pragma unroll
        for (int ni = 0; ni < 4; ni++)
          acc[mi][ni] = __builtin_amdgcn_mfma_f32_16x16x32_bf16(af[mi], bfr[ni], acc[mi][ni], 0, 0, 0);
    }
    __syncthreads();
    buf ^= 1;
  }
#pragma unroll
  for (int mi = 0; mi < 4; mi++)
#pragma unroll
    for (int ni = 0; ni < 4; ni++) {
      int row = m0 + wm + mi * 16 + quad * 4;
      int coln = n0 + wn + ni * 16 + l15;
#pragma unroll
      for (int r = 0; r < 4; r++)
        C[(size_t)(row + r) * ldc + coln] = acc[mi][ni][r];
    }
}

// ---------------- flash attention (causal, GQA), block-cooperative LDS staging ----------
// EXACT round-4 version (best measured: 45.0us) — 4 waves, QBLK=64, reg-staged dbuf.
__global__ __launch_bounds__(256, 4) void attn_kernel(const __bf16* __restrict__ Q,
                                                      const __bf16* __restrict__ Kc,
                                                      const __bf16* __restrict__ VT,
                                                      __bf16* __restrict__ Ob) {
  int px = blockIdx.x, h = blockIdx.y, b = blockIdx.z;
  int u = (px + 2 * (h & 7)) & 31;
  int qt = (((h >> 3) ^ b) & 1) ? (31 - u) : u;
  int wid = threadIdx.x >> 6, lane = threadIdx.x & 63;
  int l15 = lane & 15, quad = lane >> 4;
  int q0 = qt * 64 + wid * 16;
  int kvh = h >> 2; // N_REP = 4
  const __bf16* Qh = Q + (((size_t)b * NH_ + h) * S_ + q0) * HD_;
  const __bf16* Kh = Kc + ((size_t)b * NKV_ + kvh) * S_ * HD_;
  const __bf16* Vh = VT + ((size_t)b * NKV_ + kvh) * (size_t)HD_ * VP_;
  __shared__ __align__(16) __bf16 Ks[64][72]; // [kv][hd]
  __shared__ __align__(16) __bf16 Vs[64][72]; // [hd][kv]
  __shared__ __align__(16) __bf16 Pst[4][16][72];
  __bf16 (*P)[72] = Pst[wid];

  int srow = threadIdx.x >> 3;         // 0..31
  int scol = (threadIdx.x & 7) * 8;    // element offset 0..56

  bfx8 qf0, qf1;
  {
    const __bf16* qp = Qh + l15 * HD_ + quad * 8;
    qf0 = *(const bfx8*)qp;
    qf1 = *(const bfx8*)(qp + 32);
  }
  floatx4 oacc[4] = {};
  float ps = 0.f;
  int ntiles = qt + 1; // causal, block-uniform
  bfx8 kpre0, kpre1, vpre0, vpre1;
  kpre0 = *(const bfx8*)&Kh[(size_t)srow * HD_ + scol];
  kpre1 = *(const bfx8*)&Kh[(size_t)(srow + 32) * HD_ + scol];
  vpre0 = *(const bfx8*)&Vh[(size_t)srow * VP_ + scol];
  vpre1 = *(const bfx8*)&Vh[(size_t)(srow + 32) * VP_ + scol];
  for (int kt = 0; kt < ntiles; kt++) {
    int kv0 = kt * 64;
    int dq = q0 - kv0;
    __syncthreads();
    *(bfx8*)&Ks[srow][scol] = kpre0;
    *(bfx8*)&Ks[srow + 32][scol] = kpre1;
    *(bfx8*)&Vs[srow][scol] = vpre0;
    *(bfx8*)&Vs[srow + 32][scol] = vpre1;
    __syncthreads();
    if (kt + 1 < ntiles) {
      int kn = kv0 + 64;
      kpre0 = *(const bfx8*)&Kh[(size_t)(kn + srow) * HD_ + scol];
      kpre1 = *(const bfx8*)&Kh[(size_t)(kn + srow + 32) * HD_ + scol];
      vpre0 = *(const bfx8*)&Vh[(size_t)srow * VP_ + kn + scol];
      vpre1 = *(const bfx8*)&Vh[(size_t)(srow + 32) * VP_ + kn + scol];
    }
    floatx4 sf[4];
#pragma unroll
    for (int nt = 0; nt < 4; nt++) {
      bfx8 kf0 = *(const bfx8*)&Ks[nt * 16 + l15][quad * 8];
      bfx8 kf1 = *(const bfx8*)&Ks[nt * 16 + l15][32 + quad * 8];
      floatx4 z = {0.f, 0.f, 0.f, 0.f};
      z = __builtin_amdgcn_mfma_f32_16x16x32_bf16(kf0, qf0, z, 0, 0, 0);
      sf[nt] = __builtin_amdgcn_mfma_f32_16x16x32_bf16(kf1, qf1, z, 0, 0, 0);
    }
#pragma unroll
    for (int nt = 0; nt < 4; nt++) {
      bfx4 pk;
#pragma unroll
      for (int r = 0; r < 4; r++) {
        int kvrel = nt * 16 + quad * 4 + r;
        float p = __expf(sf[nt][r] * 0.125f);
        p = (kvrel - l15 > dq) ? 0.f : p;
        ps += p;
        pk[r] = (__bf16)p;
      }
      *(bfx4*)&P[l15][nt * 16 + quad * 4] = pk;
    }
    bfx8 pa0 = *(const bfx8*)&P[l15][quad * 8];
    bfx8 pa1 = *(const bfx8*)&P[l15][32 + quad * 8];
#pragma unroll
    for (int ot = 0; ot < 4; ot++) {
      bfx8 vf0 = *(const bfx8*)&Vs[ot * 16 + l15][quad * 8];
      bfx8 vf1 = *(const bfx8*)&Vs[ot * 16 + l15][32 + quad * 8];
      oacc[ot] = __builtin_amdgcn_mfma_f32_16x16x32_bf16(pa0, vf0, oacc[ot], 0, 0, 0);
      oacc[ot] = __builtin_amdgcn_mfma_f32_16x16x32_bf16(pa1, vf1, oacc[ot], 0, 0, 0);
    }
  }
  ps += __shfl_xor(ps, 16);
  ps += __shfl_xor(ps, 32);
  float rl[4];
#pragma unroll
  for (int r = 0; r < 4; r++) rl[r] = 1.0f / __shfl(ps, quad * 4 + r);
#pragma unroll
  for (int ot = 0; ot < 4; ot++)
#pragma unroll
    for (int r = 0; r < 4; r++) {
      float val = oacc[ot][r] * rl[r];
      Ob[((size_t)b * S_ + q0 + quad * 4 + r) * AP_ + h * HD_ + ot * 16 + l15] = (__bf16)val;
    }
}

extern "C" void kernel_launch(void* const* d_in, const int* in_sizes, int n_in,
                              void* d_out, int out_size, void* d_ws, size_t ws_size,
                              hipStream_t stream) {
  const float* x   = (const float*)d_in[0];
  const float* cosT = (const float*)d_in[1];
  const float* sinT = (const float*)d_in[2];
  const float* wq  = (const float*)d_in[3];
  const float* wk  = (const float*)d_in[4];
  const float* wv  = (const float*)d_in[5];
  const float* wo  = (const float*)d_in[6];
  const float* qw  = (const float*)d_in[7];
  const float* kw  = (const float*)d_in[8];
  float* out = (float*)d_out;

  char* w = (char*)d_ws;
  // Straight-line workspace (fused gemm reads xbf while writing Q/K/VT; no aliasing):
  __bf16* xbf   = (__bf16*)(w);                        // 4096*2112*2 = 17,301,504
  __bf16* wqkvT = (__bf16*)(w + 17301504);             // 1536*2112*2 =  6,488,064
  __bf16* woT   = (__bf16*)(w + 23789568);             // 2048*1088*2 =  4,456,448
  __bf16* Qb    = (__bf16*)(w + 28246016);             //  8,388,608
  __bf16* Kb    = (__bf16*)(w + 36634624);             //  2,097,152
  __bf16* VTb   = (__bf16*)(w + 38731776);             // 2*4*64*2112*2 = 2,162,688
  __bf16* attnO = (__bf16*)(w + 40894464);             // 4096*1088*2 = 8,912,896 (end 49,807,360)

  // fused prep: cast (4096 blocks) + wq/wk/wv/wo transposes (2048+512+512+2048)
  prep_kernel<<<M_ + 5120, 256, 0, stream>>>(x, wq, wk, wv, wo, xbf, wqkvT, woT);
  // QKV GEMM with fused RMSNorm+RoPE+layout epilogue: 128x128 dbuf, grid 12 x 32 = 384
  gemm_qkv_fused<<<dim3(NQKV_ / 128, M_ / 128), 256, 0, stream>>>(
      xbf, wqkvT, cosT, sinT, qw, kw, Qb, Kb, VTb);
  // attention: QBLK=64, 4 waves, grid 32 x 16 x 2 = 1024 blocks (round-4 exact)
  attn_kernel<<<dim3(32, NH_, B_), 256, 0, stream>>>(Qb, Kb, VTb, attnO);
  // output GEMM, 256x128 dbuf: grid 16 x 16 = 256 blocks
  gemm_bf16_f32<<<dim3(H_ / 128, M_ / 256), 512, 0, stream>>>(
      attnO, woT, out, M_, H_, HQ_, AP_, AP_, H_);
}